// Round 4
// baseline (155.508 us; speedup 1.0000x reference)
//
#include <hip/hip_runtime.h>
#include <stdint.h>

#define BS 8192
#define DD 128
#define SPLIT 16  // j-slices per 128-row block; grid = 64*SPLIT = 1024 blocks

typedef __attribute__((ext_vector_type(8))) short short8;
typedef __attribute__((ext_vector_type(4))) float float4v;

#if __has_builtin(__builtin_amdgcn_exp2f)
#define EXP2(x) __builtin_amdgcn_exp2f(x)
#else
#define EXP2(x) exp2f(x)
#endif

__device__ __forceinline__ float bf2f(short s) {
  union { unsigned u; float f; } c;
  c.u = ((unsigned)(unsigned short)s) << 16;
  return c.f;
}
__device__ __forceinline__ short f2bf(float f) {
  union { float f; unsigned u; } c; c.f = f;
  unsigned u = c.u + 0x7FFFu + ((c.u >> 16) & 1u);
  return (short)(u >> 16);
}

// K1: normalize rows (f32 + packed-bf16 copies), per-class column sums, counts,
// f32 label mask mf[], and zero-init of Zr/Ur/Vr/out (all downstream of this
// kernel in stream order, so no separate fill nodes).
__global__ __launch_bounds__(256) void k_norm(const float* __restrict__ data,
                                              const int* __restrict__ label,
                                              unsigned int* __restrict__ xnb32,
                                              float* __restrict__ xnf,
                                              float* __restrict__ gh,
                                              int* __restrict__ cnt,
                                              float* __restrict__ Zr,
                                              float* __restrict__ Ur,
                                              float* __restrict__ Vr,
                                              float* __restrict__ mf,
                                              float* __restrict__ out) {
  __shared__ float sh[256];
  __shared__ int shc[2];
  int tid = threadIdx.x, wave = tid >> 6, lane = tid & 63;
  if (tid < 2) shc[tid] = 0;
  sh[tid] = 0.f;
  if (tid < 32) {  // zero this block's accumulator slice (pre-poisoned 0xAA)
    int row = blockIdx.x * 32 + tid;
    Zr[row] = 0.f; Ur[row] = 0.f; Vr[row] = 0.f;
    mf[row] = (label[row] == 0) ? 1.f : 0.f;
  }
  if (blockIdx.x == 0 && tid == 0) out[0] = 0.f;
  __syncthreads();
  float a00 = 0.f, a01 = 0.f, a10 = 0.f, a11 = 0.f;
  int c0 = 0, c1 = 0;
  int rbase = blockIdx.x * 32 + wave * 8;
  for (int r = 0; r < 8; ++r) {
    int row = rbase + r;
    float2 v = *(const float2*)&data[row * DD + lane * 2];
    float ss = v.x * v.x + v.y * v.y;
    for (int off = 32; off; off >>= 1) ss += __shfl_xor(ss, off);
    float rn = 1.f / fmaxf(sqrtf(ss), 1e-12f);  // F.normalize eps clamp
    float x0 = v.x * rn, x1 = v.y * rn;
    *(float2*)&xnf[row * DD + lane * 2] = make_float2(x0, x1);
    unsigned int pk = (unsigned int)(unsigned short)f2bf(x0) |
                      ((unsigned int)(unsigned short)f2bf(x1) << 16);
    xnb32[row * 64 + lane] = pk;
    int lab = label[row];  // wave-uniform
    if (lab == 0) { a00 += x0; a01 += x1; c0++; }
    else          { a10 += x0; a11 += x1; c1++; }
  }
  atomicAdd(&sh[2 * lane], a00);
  atomicAdd(&sh[2 * lane + 1], a01);
  atomicAdd(&sh[128 + 2 * lane], a10);
  atomicAdd(&sh[128 + 2 * lane + 1], a11);
  if (lane == 0) { atomicAdd(&shc[0], c0); atomicAdd(&shc[1], c1); }
  __syncthreads();
  atomicAdd(&gh[tid], sh[tid]);
  if (tid < 2) atomicAdd(&cnt[tid], shc[tid]);
}

// K3: flash-style Gram-row reductions — NO LDS, NO barriers.
// Round-3 post-mortem: the 2-barrier global_load_lds tile loop was latency-bound
// (Occupancy 18%, all pipes <35%): every tile paid a vmcnt(0)+barrier drain that
// no wave in the block could overlap. xnb is 2 MB = L2-resident per XCD, so B
// fragments are loaded straight from global (per jo: 16 rows x 64B = 16 coalesced
// cache lines) and the compiler pipelines loads vs MFMA with fine-grained vmcnt —
// the structure the barrier loop cannot express.
// A pre-scaled by exp(scale)*log2(e): MFMA emits l*log2e, epilogue is raw v_exp_f32.
__global__ __launch_bounds__(256) void k_main(const unsigned short* __restrict__ xnb,
                                              const int* __restrict__ label,
                                              const float* __restrict__ mf,
                                              const float* __restrict__ scale,
                                              float* __restrict__ Zr,
                                              float* __restrict__ Ur,
                                              float* __restrict__ Vr) {
  int tid = threadIdx.x, wave = tid >> 6, lane = tid & 63;
  int quad = lane >> 4, col = lane & 15;
  int rb = blockIdx.x / SPLIT, sl = blockIdx.x % SPLIT;
  float se2 = __expf(scale[0]) * 1.4426950408889634f;  // exp(scale) * log2(e)

  // A fragments: A[m=lane&15][k=quad*8+i], ktiles t=0..3; two row-sets s=0,1
  short8 afrag[2][4];
  int labI[2][4];
#pragma unroll
  for (int s = 0; s < 2; ++s) {
    int arow = rb * 128 + s * 64 + wave * 16 + col;
    const short* ap = (const short*)xnb + (size_t)arow * DD;
#pragma unroll
    for (int t = 0; t < 4; ++t) {
      short8 a = *(const short8*)(ap + t * 32 + quad * 8);
#pragma unroll
      for (int i = 0; i < 8; ++i) a[i] = f2bf(bf2f(a[i]) * se2);
      afrag[s][t] = a;
    }
#pragma unroll
    for (int r = 0; r < 4; ++r)
      labI[s][r] = label[rb * 128 + s * 64 + wave * 16 + quad * 4 + r];
  }

  float Z[2][4] = {}, U[2][4] = {}, V0[2][4] = {};

  const short* xs = (const short*)xnb;
#pragma unroll 2
  for (int j0 = sl * (BS / SPLIT); j0 < (sl + 1) * (BS / SPLIT); j0 += 16) {
    int jc = j0 + col;
    float m0 = mf[jc];  // f32 same-class-0 mask, L1-resident (32 KB)
    const short* bp = xs + (size_t)jc * DD + quad * 8;
    short8 b0 = *(const short8*)(bp);
    short8 b1 = *(const short8*)(bp + 32);
    short8 b2 = *(const short8*)(bp + 64);
    short8 b3 = *(const short8*)(bp + 96);
    float4v c0 = {0.f, 0.f, 0.f, 0.f}, c1 = {0.f, 0.f, 0.f, 0.f};
    c0 = __builtin_amdgcn_mfma_f32_16x16x32_bf16(afrag[0][0], b0, c0, 0, 0, 0);
    c1 = __builtin_amdgcn_mfma_f32_16x16x32_bf16(afrag[1][0], b0, c1, 0, 0, 0);
    c0 = __builtin_amdgcn_mfma_f32_16x16x32_bf16(afrag[0][1], b1, c0, 0, 0, 0);
    c1 = __builtin_amdgcn_mfma_f32_16x16x32_bf16(afrag[1][1], b1, c1, 0, 0, 0);
    c0 = __builtin_amdgcn_mfma_f32_16x16x32_bf16(afrag[0][2], b2, c0, 0, 0, 0);
    c1 = __builtin_amdgcn_mfma_f32_16x16x32_bf16(afrag[1][2], b2, c1, 0, 0, 0);
    c0 = __builtin_amdgcn_mfma_f32_16x16x32_bf16(afrag[0][3], b3, c0, 0, 0, 0);
    c1 = __builtin_amdgcn_mfma_f32_16x16x32_bf16(afrag[1][3], b3, c1, 0, 0, 0);
#pragma unroll
    for (int r = 0; r < 4; ++r) {  // C/D: col=lane&15, row=quad*4+r (m89)
      float l0 = c0[r], e0 = EXP2(l0);  // l2 <= 20.6 -> e <= 1.6e6, fp32-safe
      Z[0][r] += e0; U[0][r] += e0 * l0; V0[0][r] += m0 * e0;
      float l1 = c1[r], e1 = EXP2(l1);
      Z[1][r] += e1; U[1][r] += e1 * l1; V0[1][r] += m0 * e1;
    }
  }
  // reduce across the 16 column-lanes sharing each row
#pragma unroll
  for (int s = 0; s < 2; ++s)
#pragma unroll
    for (int r = 0; r < 4; ++r)
#pragma unroll
      for (int off = 1; off < 16; off <<= 1) {
        Z[s][r] += __shfl_xor(Z[s][r], off);
        U[s][r] += __shfl_xor(U[s][r], off);
        V0[s][r] += __shfl_xor(V0[s][r], off);
      }
  if (col == 0) {
#pragma unroll
    for (int s = 0; s < 2; ++s)
#pragma unroll
      for (int r = 0; r < 4; ++r) {
        int row = rb * 128 + s * 64 + wave * 16 + quad * 4 + r;
        float v = (labI[s][r] == 0) ? V0[s][r] : (Z[s][r] - V0[s][r]);
        atomicAdd(&Zr[row], Z[s][r]);
        atomicAdd(&Ur[row], U[s][r] * 0.6931471805599453f);  // U2*ln2 -> true units
        atomicAdd(&Vr[row], v);
      }
  }
}

// K4: per-row loss. S,T via closed-form dots with class sums; M and log(Zq) cancel.
__global__ __launch_bounds__(256) void k_final(const float* __restrict__ xnf,
                                               const int* __restrict__ label,
                                               const float* __restrict__ scale,
                                               const float* __restrict__ gh,
                                               const int* __restrict__ cnt,
                                               const float* __restrict__ Zr,
                                               const float* __restrict__ Ur,
                                               const float* __restrict__ Vr,
                                               float* __restrict__ out) {
  __shared__ float bsum[4];
  int tid = threadIdx.x, wave = tid >> 6, lane = tid & 63;
  float se = __expf(scale[0]);
  float h0a = gh[2 * lane], h0b = gh[2 * lane + 1];
  float h1a = gh[128 + 2 * lane], h1b = gh[128 + 2 * lane + 1];
  float ga = h0a + h1a, gb = h0b + h1b;  // g = h0 + h1
  float c0 = (float)cnt[0], c1 = (float)cnt[1];
  float local = 0.f;
  int rbase = blockIdx.x * 32 + wave * 8;
  for (int r = 0; r < 8; ++r) {
    int row = rbase + r;
    float2 x = *(const float2*)&xnf[row * DD + lane * 2];
    int lab = label[row];
    float sg = x.x * ga + x.y * gb;
    float sh_ = (lab == 0) ? (x.x * h0a + x.y * h0b) : (x.x * h1a + x.y * h1b);
    for (int off = 32; off; off >>= 1) {
      sg += __shfl_xor(sg, off);
      sh_ += __shfl_xor(sh_, off);
    }
    if (lane == 0) {
      float cc = (lab == 0) ? c0 : c1;
      float a = __expf(1.f / cc);
      float Zq = cc * a + ((float)BS - cc);
      float S = se * sg, T = se * sh_;
      float Z = Zr[row], U = Ur[row], V = Vr[row];
      // loss_i = a/Zq - (S+(a-1)T)/Zq + U/Z - V/(c*Z)   (M_i, log Zq cancelled)
      local += a / Zq - (S + (a - 1.f) * T) / Zq + U / Z - V / (cc * Z);
    }
  }
  if (lane == 0) bsum[wave] = local;
  __syncthreads();
  if (tid == 0) {
    float s = bsum[0] + bsum[1] + bsum[2] + bsum[3];
    atomicAdd(out, s * (0.5f / (float)BS));
  }
}

extern "C" void kernel_launch(void* const* d_in, const int* in_sizes, int n_in,
                              void* d_out, int out_size, void* d_ws, size_t ws_size,
                              hipStream_t stream) {
  const float* data = (const float*)d_in[0];
  const float* scale = (const float*)d_in[1];
  const int* label = (const int*)d_in[2];
  char* ws = (char*)d_ws;
  // ws layout (bytes):
  //   0        xnb  bf16[8192*128]   2 MB
  //   2097152  xnf  f32 [8192*128]   4 MB
  //   6291456  Zr   f32 [8192]
  //   6324224  Ur   f32 [8192]
  //   6356992  Vr   f32 [8192]
  //   6389760  gh   f32 [256]  (h0[128], h1[128])
  //   6390784  cnt  int [2]
  //   6390800  mf   f32 [8192]  (label==0 ? 1.0 : 0.0)
  unsigned short* xnb = (unsigned short*)ws;
  unsigned int* xnb32 = (unsigned int*)ws;
  float* xnf = (float*)(ws + 2097152);
  float* Zr = (float*)(ws + 6291456);
  float* Ur = (float*)(ws + 6324224);
  float* Vr = (float*)(ws + 6356992);
  float* gh = (float*)(ws + 6389760);
  int* cnt = (int*)(ws + 6390784);
  float* mf = (float*)(ws + 6390800);

  // gh+cnt only (1032 B); Zr/Ur/Vr/mf + d_out are initialized inside k_norm
  hipMemsetAsync(ws + 6389760, 0, 1032, stream);

  k_norm<<<256, 256, 0, stream>>>(data, label, xnb32, xnf, gh, cnt, Zr, Ur, Vr, mf,
                                  (float*)d_out);
  k_main<<<64 * SPLIT, 256, 0, stream>>>(xnb, label, mf, scale, Zr, Ur, Vr);
  k_final<<<256, 256, 0, stream>>>(xnf, label, scale, gh, cnt, Zr, Ur, Vr, (float*)d_out);
}

// Round 5
// 121.441 us; speedup vs baseline: 1.2805x; 1.2805x over previous
//
#include <hip/hip_runtime.h>
#include <stdint.h>

#define BS 8192
#define DD 128
#define SPLIT 16  // j-slices per 128-row block; grid = 64*SPLIT = 1024 blocks

typedef __attribute__((ext_vector_type(8))) short short8;
typedef __attribute__((ext_vector_type(4))) float float4v;

#if __has_builtin(__builtin_amdgcn_exp2f)
#define EXP2(x) __builtin_amdgcn_exp2f(x)
#else
#define EXP2(x) exp2f(x)
#endif

__device__ __forceinline__ float bf2f(short s) {
  union { unsigned u; float f; } c;
  c.u = ((unsigned)(unsigned short)s) << 16;
  return c.f;
}
__device__ __forceinline__ short f2bf(float f) {
  union { float f; unsigned u; } c; c.f = f;
  unsigned u = c.u + 0x7FFFu + ((c.u >> 16) & 1u);
  return (short)(u >> 16);
}

// K1: normalize rows (f32 + packed-bf16 copies), per-class column sums, counts,
// f32 label mask mf[], zero-init of Zr/Ur/Vr/out (all stream-ordered before use).
__global__ __launch_bounds__(256) void k_norm(const float* __restrict__ data,
                                              const int* __restrict__ label,
                                              unsigned int* __restrict__ xnb32,
                                              float* __restrict__ xnf,
                                              float* __restrict__ gh,
                                              int* __restrict__ cnt,
                                              float* __restrict__ Zr,
                                              float* __restrict__ Ur,
                                              float* __restrict__ Vr,
                                              float* __restrict__ mf,
                                              float* __restrict__ out) {
  __shared__ float sh[256];
  __shared__ int shc[2];
  int tid = threadIdx.x, wave = tid >> 6, lane = tid & 63;
  if (tid < 2) shc[tid] = 0;
  sh[tid] = 0.f;
  if (tid < 32) {  // zero this block's accumulator slice (pre-poisoned 0xAA)
    int row = blockIdx.x * 32 + tid;
    Zr[row] = 0.f; Ur[row] = 0.f; Vr[row] = 0.f;
    mf[row] = (label[row] == 0) ? 1.f : 0.f;
  }
  if (blockIdx.x == 0 && tid == 0) out[0] = 0.f;
  __syncthreads();
  float a00 = 0.f, a01 = 0.f, a10 = 0.f, a11 = 0.f;
  int c0 = 0, c1 = 0;
  int rbase = blockIdx.x * 32 + wave * 8;
  for (int r = 0; r < 8; ++r) {
    int row = rbase + r;
    float2 v = *(const float2*)&data[row * DD + lane * 2];
    float ss = v.x * v.x + v.y * v.y;
    for (int off = 32; off; off >>= 1) ss += __shfl_xor(ss, off);
    float rn = 1.f / fmaxf(sqrtf(ss), 1e-12f);  // F.normalize eps clamp
    float x0 = v.x * rn, x1 = v.y * rn;
    *(float2*)&xnf[row * DD + lane * 2] = make_float2(x0, x1);
    unsigned int pk = (unsigned int)(unsigned short)f2bf(x0) |
                      ((unsigned int)(unsigned short)f2bf(x1) << 16);
    xnb32[row * 64 + lane] = pk;
    int lab = label[row];  // wave-uniform
    if (lab == 0) { a00 += x0; a01 += x1; c0++; }
    else          { a10 += x0; a11 += x1; c1++; }
  }
  atomicAdd(&sh[2 * lane], a00);
  atomicAdd(&sh[2 * lane + 1], a01);
  atomicAdd(&sh[128 + 2 * lane], a10);
  atomicAdd(&sh[128 + 2 * lane + 1], a11);
  if (lane == 0) { atomicAdd(&shc[0], c0); atomicAdd(&shc[1], c1); }
  __syncthreads();
  atomicAdd(&gh[tid], sh[tid]);
  if (tid < 2) atomicAdd(&cnt[tid], shc[tid]);
}

// ---- K3 helpers -----------------------------------------------------------
// Stage 64 rows x 128 cols bf16 (16 KB) into an LDS tile via global_load_lds,
// XOR-swizzled: LDS (row r, chunk c) holds global chunk c ^ (r&15).
__device__ __forceinline__ void stage_tile(const char* srcbase, int j0,
                                           char* dstbase, int tid) {
  int rowloc = tid >> 4;          // 0..15: row (mod 16) this lane stages
  int swz = (tid & 15) ^ rowloc;  // which 16B chunk of that row
  char* dst = dstbase + tid * 16;
#pragma unroll
  for (int p = 0; p < 4; ++p) {
    const char* src = srcbase + (size_t)(j0 + p * 16 + rowloc) * 256 + swz * 16;
    __builtin_amdgcn_global_load_lds(
        (const __attribute__((address_space(1))) void*)(uintptr_t)src,
        (__attribute__((address_space(3))) void*)(uintptr_t)(dst + p * 4096), 16, 0, 0);
  }
}

// Consume one 64-col tile: 8 MFMA chains (2 row-sets) + streaming exp epilogue.
__device__ __forceinline__ void consume_tile(const short* __restrict__ tile, int j0,
                                             const float* __restrict__ mf,
                                             const short8 afrag[2][4], int quad, int col,
                                             float Z[2][4], float U[2][4], float V0[2][4]) {
#pragma unroll
  for (int jo = 0; jo < 4; ++jo) {
    int jc = j0 + jo * 16 + col;
    float m0 = mf[jc];  // f32 same-class-0 mask (L1/L2-resident)
    float4v c0 = {0.f, 0.f, 0.f, 0.f}, c1 = {0.f, 0.f, 0.f, 0.f};
    const short* bp = tile + (jo * 16 + col) * DD;
#pragma unroll
    for (int t = 0; t < 4; ++t) {
      short8 b = *(const short8*)(bp + ((t * 4 + quad) ^ col) * 8);
      c0 = __builtin_amdgcn_mfma_f32_16x16x32_bf16(afrag[0][t], b, c0, 0, 0, 0);
      c1 = __builtin_amdgcn_mfma_f32_16x16x32_bf16(afrag[1][t], b, c1, 0, 0, 0);
    }
#pragma unroll
    for (int r = 0; r < 4; ++r) {  // C/D: col=lane&15, row=quad*4+r (m89)
      float l0 = c0[r], e0 = EXP2(l0);  // log2-domain: l2 <= 20.6, fp32-safe
      Z[0][r] += e0; U[0][r] += e0 * l0; V0[0][r] += m0 * e0;
      float l1 = c1[r], e1 = EXP2(l1);
      Z[1][r] += e1; U[1][r] += e1 * l1; V0[1][r] += m0 * e1;
    }
  }
}

// K3: flash-style Gram-row reductions, shared-LDS staging, DOUBLE-BUFFERED.
// Round-4 post-mortem: both prior structures were latency-bound (all pipes idle).
// Here the stage of tile t+1 is issued BEFORE consuming tile t, so the barrier's
// vmcnt(0) drain overlaps ~700 cyc of compute instead of stalling bare. Two
// DISTINCT __shared__ arrays keep the ds_reads of one buffer alias-independent
// of the in-flight LDS-DMA into the other (single-array dbuf would re-serialize).
__global__ __launch_bounds__(256) void k_main(const unsigned short* __restrict__ xnb,
                                              const int* __restrict__ label,
                                              const float* __restrict__ mf,
                                              const float* __restrict__ scale,
                                              float* __restrict__ Zr,
                                              float* __restrict__ Ur,
                                              float* __restrict__ Vr) {
  __shared__ short tileA[64 * DD];  // 16 KB
  __shared__ short tileB[64 * DD];  // 16 KB
  int tid = threadIdx.x, wave = tid >> 6, lane = tid & 63;
  int quad = lane >> 4, col = lane & 15;
  int rb = blockIdx.x / SPLIT, sl = blockIdx.x % SPLIT;
  float se2 = __expf(scale[0]) * 1.4426950408889634f;  // exp(scale)*log2(e)

  // A fragments: A[m=lane&15][k=quad*8+i], ktiles t=0..3; two row-sets s=0,1
  short8 afrag[2][4];
  int labI[2][4];
#pragma unroll
  for (int s = 0; s < 2; ++s) {
    int arow = rb * 128 + s * 64 + wave * 16 + col;
    const short* ap = (const short*)xnb + (size_t)arow * DD;
#pragma unroll
    for (int t = 0; t < 4; ++t) {
      short8 a = *(const short8*)(ap + t * 32 + quad * 8);
#pragma unroll
      for (int i = 0; i < 8; ++i) a[i] = f2bf(bf2f(a[i]) * se2);
      afrag[s][t] = a;
    }
#pragma unroll
    for (int r = 0; r < 4; ++r)
      labI[s][r] = label[rb * 128 + s * 64 + wave * 16 + quad * 4 + r];
  }

  float Z[2][4] = {}, U[2][4] = {}, V0[2][4] = {};

  const char* srcbase = (const char*)xnb;
  int jbase = sl * (BS / SPLIT), jend = jbase + (BS / SPLIT);

  stage_tile(srcbase, jbase, (char*)tileA, tid);
  __syncthreads();  // drain first A
  for (int j0 = jbase; j0 < jend; j0 += 128) {
    stage_tile(srcbase, j0 + 64, (char*)tileB, tid);        // B loads in flight...
    consume_tile(tileA, j0, mf, afrag, quad, col, Z, U, V0);  // ...over A compute
    __syncthreads();  // drains B; protects A overwrite
    int jn = (j0 + 128 < jend) ? (j0 + 128) : jbase;  // wave-uniform; dummy on last
    stage_tile(srcbase, jn, (char*)tileA, tid);
    consume_tile(tileB, j0 + 64, mf, afrag, quad, col, Z, U, V0);
    __syncthreads();  // drains A; protects B overwrite
  }

  // reduce across the 16 column-lanes sharing each row
#pragma unroll
  for (int s = 0; s < 2; ++s)
#pragma unroll
    for (int r = 0; r < 4; ++r)
#pragma unroll
      for (int off = 1; off < 16; off <<= 1) {
        Z[s][r] += __shfl_xor(Z[s][r], off);
        U[s][r] += __shfl_xor(U[s][r], off);
        V0[s][r] += __shfl_xor(V0[s][r], off);
      }
  if (col == 0) {
#pragma unroll
    for (int s = 0; s < 2; ++s)
#pragma unroll
      for (int r = 0; r < 4; ++r) {
        int row = rb * 128 + s * 64 + wave * 16 + quad * 4 + r;
        float v = (labI[s][r] == 0) ? V0[s][r] : (Z[s][r] - V0[s][r]);
        atomicAdd(&Zr[row], Z[s][r]);
        atomicAdd(&Ur[row], U[s][r] * 0.6931471805599453f);  // log2-domain -> nats
        atomicAdd(&Vr[row], v);
      }
  }
}

// K4: per-row loss. S,T via closed-form dots with class sums; M and log(Zq) cancel.
__global__ __launch_bounds__(256) void k_final(const float* __restrict__ xnf,
                                               const int* __restrict__ label,
                                               const float* __restrict__ scale,
                                               const float* __restrict__ gh,
                                               const int* __restrict__ cnt,
                                               const float* __restrict__ Zr,
                                               const float* __restrict__ Ur,
                                               const float* __restrict__ Vr,
                                               float* __restrict__ out) {
  __shared__ float bsum[4];
  int tid = threadIdx.x, wave = tid >> 6, lane = tid & 63;
  float se = __expf(scale[0]);
  float h0a = gh[2 * lane], h0b = gh[2 * lane + 1];
  float h1a = gh[128 + 2 * lane], h1b = gh[128 + 2 * lane + 1];
  float ga = h0a + h1a, gb = h0b + h1b;  // g = h0 + h1
  float c0 = (float)cnt[0], c1 = (float)cnt[1];
  float local = 0.f;
  int rbase = blockIdx.x * 32 + wave * 8;
  for (int r = 0; r < 8; ++r) {
    int row = rbase + r;
    float2 x = *(const float2*)&xnf[row * DD + lane * 2];
    int lab = label[row];
    float sg = x.x * ga + x.y * gb;
    float sh_ = (lab == 0) ? (x.x * h0a + x.y * h0b) : (x.x * h1a + x.y * h1b);
    for (int off = 32; off; off >>= 1) {
      sg += __shfl_xor(sg, off);
      sh_ += __shfl_xor(sh_, off);
    }
    if (lane == 0) {
      float cc = (lab == 0) ? c0 : c1;
      float a = __expf(1.f / cc);
      float Zq = cc * a + ((float)BS - cc);
      float S = se * sg, T = se * sh_;
      float Z = Zr[row], U = Ur[row], V = Vr[row];
      // loss_i = a/Zq - (S+(a-1)T)/Zq + U/Z - V/(c*Z)   (M_i, log Zq cancelled)
      local += a / Zq - (S + (a - 1.f) * T) / Zq + U / Z - V / (cc * Z);
    }
  }
  if (lane == 0) bsum[wave] = local;
  __syncthreads();
  if (tid == 0) {
    float s = bsum[0] + bsum[1] + bsum[2] + bsum[3];
    atomicAdd(out, s * (0.5f / (float)BS));
  }
}

extern "C" void kernel_launch(void* const* d_in, const int* in_sizes, int n_in,
                              void* d_out, int out_size, void* d_ws, size_t ws_size,
                              hipStream_t stream) {
  const float* data = (const float*)d_in[0];
  const float* scale = (const float*)d_in[1];
  const int* label = (const int*)d_in[2];
  char* ws = (char*)d_ws;
  // ws layout (bytes):
  //   0        xnb  bf16[8192*128]   2 MB
  //   2097152  xnf  f32 [8192*128]   4 MB
  //   6291456  Zr   f32 [8192]
  //   6324224  Ur   f32 [8192]
  //   6356992  Vr   f32 [8192]
  //   6389760  gh   f32 [256]  (h0[128], h1[128])
  //   6390784  cnt  int [2]
  //   6390800  mf   f32 [8192]  (label==0 ? 1.0 : 0.0)
  unsigned short* xnb = (unsigned short*)ws;
  unsigned int* xnb32 = (unsigned int*)ws;
  float* xnf = (float*)(ws + 2097152);
  float* Zr = (float*)(ws + 6291456);
  float* Ur = (float*)(ws + 6324224);
  float* Vr = (float*)(ws + 6356992);
  float* gh = (float*)(ws + 6389760);
  int* cnt = (int*)(ws + 6390784);
  float* mf = (float*)(ws + 6390800);

  // gh+cnt only (1032 B); Zr/Ur/Vr/mf + d_out are initialized inside k_norm
  hipMemsetAsync(ws + 6389760, 0, 1032, stream);

  k_norm<<<256, 256, 0, stream>>>(data, label, xnb32, xnf, gh, cnt, Zr, Ur, Vr, mf,
                                  (float*)d_out);
  k_main<<<64 * SPLIT, 256, 0, stream>>>(xnb, label, mf, scale, Zr, Ur, Vr);
  k_final<<<256, 256, 0, stream>>>(xnf, label, scale, gh, cnt, Zr, Ur, Vr, (float*)d_out);
}